// Round 6
// baseline (453.853 us; speedup 1.0000x reference)
//
#include <hip/hip_runtime.h>
#include <cmath>

#define B_   4
#define L_   1024
#define H_   768
#define NH_  12
#define NE_  30
#define M_   6
#define P_   600
#define EMB_ 768
#define BS_  16
#define NC_  97

typedef __bf16 bf16x8 __attribute__((ext_vector_type(8)));
typedef float floatx4 __attribute__((ext_vector_type(4)));

union V16 { uint4 q; __bf16 b[8]; bf16x8 v; };
union V8  { unsigned long long u; __bf16 b[4]; };

// =================== NT MFMA core, 64x64 tile ===================
__device__ __forceinline__ void gemm_core(
    const __bf16* __restrict__ A, int lda, long aRow0,
    const __bf16* __restrict__ Bt, int ldb, long bRow0,
    int K, __bf16* sm, floatx4 acc[2][2])
{
  const int tid = threadIdx.x;
  const int lid = tid & 63, w = tid >> 6;
  const int ar = (w & 1) * 32, bc = (w >> 1) * 32;
  const int frow = lid & 15, kg = lid >> 4;
  __bf16* As = sm;             // [64][40]
  __bf16* Bs = sm + 64*40;     // [64][40]
  const int srow = tid >> 2, skq = (tid & 3) * 8;
  const __bf16* ag = A + (aRow0 + srow) * (long)lda + skq;
  const __bf16* bg = Bt + (bRow0 + srow) * (long)ldb + skq;
  for (int k0 = 0; k0 < K; k0 += 32) {
    uint4 av = *reinterpret_cast<const uint4*>(ag + k0);
    uint4 bv = *reinterpret_cast<const uint4*>(bg + k0);
    __syncthreads();
    *reinterpret_cast<uint4*>(As + srow*40 + skq) = av;
    *reinterpret_cast<uint4*>(Bs + srow*40 + skq) = bv;
    __syncthreads();
    V16 a0, a1, b0, b1;
    a0.q = *reinterpret_cast<const uint4*>(As + (ar + frow)*40 + kg*8);
    a1.q = *reinterpret_cast<const uint4*>(As + (ar + 16 + frow)*40 + kg*8);
    b0.q = *reinterpret_cast<const uint4*>(Bs + (bc + frow)*40 + kg*8);
    b1.q = *reinterpret_cast<const uint4*>(Bs + (bc + 16 + frow)*40 + kg*8);
    acc[0][0] = __builtin_amdgcn_mfma_f32_16x16x32_bf16(a0.v, b0.v, acc[0][0], 0, 0, 0);
    acc[0][1] = __builtin_amdgcn_mfma_f32_16x16x32_bf16(a0.v, b1.v, acc[0][1], 0, 0, 0);
    acc[1][0] = __builtin_amdgcn_mfma_f32_16x16x32_bf16(a1.v, b0.v, acc[1][0], 0, 0, 0);
    acc[1][1] = __builtin_amdgcn_mfma_f32_16x16x32_bf16(a1.v, b1.v, acc[1][1], 0, 0, 0);
  }
}

// =================== NN MFMA core, 64x64 tile, B from fp32 row-major [K][ldn] ==========
__device__ __forceinline__ void gemm_core_nn(
    const __bf16* __restrict__ A, int lda, long aRow0,
    const float* __restrict__ B, int ldn, int n0,
    int K, __bf16* sm, floatx4 acc[2][2])
{
  const int tid = threadIdx.x;
  const int lid = tid & 63, w = tid >> 6;
  const int ar = (w & 1) * 32, bc = (w >> 1) * 32;
  const int frow = lid & 15, kg = lid >> 4;
  __bf16* As = sm;             // [64 rows][40 k]
  __bf16* Bs = sm + 64*40;     // [64 n][40 k]
  const int srow = tid >> 2, skq = (tid & 3) * 8;
  const __bf16* ag = A + (aRow0 + srow) * (long)lda + skq;
  const int bkk = tid >> 6;    // wave-uniform k-row within pass
  const int bnn = tid & 63;
  for (int k0 = 0; k0 < K; k0 += 32) {
    uint4 av = *reinterpret_cast<const uint4*>(ag + k0);
    float bv[8];
#pragma unroll
    for (int pass = 0; pass < 8; ++pass)
      bv[pass] = B[(long)(k0 + pass*4 + bkk)*ldn + n0 + bnn];
    __syncthreads();
    *reinterpret_cast<uint4*>(As + srow*40 + skq) = av;
#pragma unroll
    for (int pass = 0; pass < 8; ++pass)
      Bs[bnn*40 + pass*4 + bkk] = (__bf16)bv[pass];
    __syncthreads();
    V16 a0, a1, b0, b1;
    a0.q = *reinterpret_cast<const uint4*>(As + (ar + frow)*40 + kg*8);
    a1.q = *reinterpret_cast<const uint4*>(As + (ar + 16 + frow)*40 + kg*8);
    b0.q = *reinterpret_cast<const uint4*>(Bs + (bc + frow)*40 + kg*8);
    b1.q = *reinterpret_cast<const uint4*>(Bs + (bc + 16 + frow)*40 + kg*8);
    acc[0][0] = __builtin_amdgcn_mfma_f32_16x16x32_bf16(a0.v, b0.v, acc[0][0], 0, 0, 0);
    acc[0][1] = __builtin_amdgcn_mfma_f32_16x16x32_bf16(a0.v, b1.v, acc[0][1], 0, 0, 0);
    acc[1][0] = __builtin_amdgcn_mfma_f32_16x16x32_bf16(a1.v, b0.v, acc[1][0], 0, 0, 0);
    acc[1][1] = __builtin_amdgcn_mfma_f32_16x16x32_bf16(a1.v, b1.v, acc[1][1], 0, 0, 0);
  }
}

// =================== NT MFMA core, 64x128 tile ===================
__device__ __forceinline__ void gemm_core_wide(
    const __bf16* __restrict__ A, int lda, long aRow0,
    const __bf16* __restrict__ Bt, int ldb, long bRow0,
    int K, __bf16* sm, floatx4 acc[2][4])
{
  const int tid = threadIdx.x;
  const int lid = tid & 63, w = tid >> 6;
  const int ar = (w & 1) * 32, bc = (w >> 1) * 64;
  const int frow = lid & 15, kg = lid >> 4;
  __bf16* As = sm;             // [64][40]
  __bf16* Bs = sm + 64*40;     // [128][40]
  const int srow = tid >> 2, skq = (tid & 3) * 8;
  const __bf16* ag = A + (aRow0 + srow) * (long)lda + skq;
  const __bf16* bg0 = Bt + (bRow0 + srow) * (long)ldb + skq;
  const __bf16* bg1 = Bt + (bRow0 + 64 + srow) * (long)ldb + skq;
  for (int k0 = 0; k0 < K; k0 += 32) {
    uint4 av  = *reinterpret_cast<const uint4*>(ag + k0);
    uint4 bv0 = *reinterpret_cast<const uint4*>(bg0 + k0);
    uint4 bv1 = *reinterpret_cast<const uint4*>(bg1 + k0);
    __syncthreads();
    *reinterpret_cast<uint4*>(As + srow*40 + skq) = av;
    *reinterpret_cast<uint4*>(Bs + srow*40 + skq) = bv0;
    *reinterpret_cast<uint4*>(Bs + (64 + srow)*40 + skq) = bv1;
    __syncthreads();
    V16 a0, a1;
    a0.q = *reinterpret_cast<const uint4*>(As + (ar + frow)*40 + kg*8);
    a1.q = *reinterpret_cast<const uint4*>(As + (ar + 16 + frow)*40 + kg*8);
#pragma unroll
    for (int q = 0; q < 4; ++q) {
      V16 bq;
      bq.q = *reinterpret_cast<const uint4*>(Bs + (bc + q*16 + frow)*40 + kg*8);
      acc[0][q] = __builtin_amdgcn_mfma_f32_16x16x32_bf16(a0.v, bq.v, acc[0][q], 0, 0, 0);
      acc[1][q] = __builtin_amdgcn_mfma_f32_16x16x32_bf16(a1.v, bq.v, acc[1][q], 0, 0, 0);
    }
  }
}

// =================== STAGE 1: fused prep ===================
// [0,2400) cvt weights | [2400,5472) transpose seq | [5472,5592) pool | [5592,7032) att
#define S1_CVT  2400
#define S1_TPS  3072
#define S1_POOL 120
#define S1_ATT  1440

__global__ __launch_bounds__(256) void k_prep(
    const float* __restrict__ seq, const float* __restrict__ att,
    const float* __restrict__ headW, const float* __restrict__ tailW,
    const float* __restrict__ clsW,
    const float* __restrict__ mmask, const int* __restrict__ midx,
    __bf16* __restrict__ Wt, __bf16* __restrict__ clsA,
    __bf16* __restrict__ seqT, __bf16* __restrict__ e_embB,
    __bf16* __restrict__ e_att)
{
  __shared__ float t[32][33];
  int blk = blockIdx.x;
  int tid = threadIdx.x;
  if (blk < S1_CVT) {
    int gid = blk*256 + tid;
    if (gid < 2*H_*384) {
      int sel = gid / (H_*384);
      int rem = gid % (H_*384);
      int o = rem / 384;
      int k4 = (rem % 384) * 4;
      const float* W = sel ? tailW : headW;
      float4 v = *reinterpret_cast<const float4*>(W + (long)o*(2*H_) + k4);
      V8 d; d.b[0]=(__bf16)v.x; d.b[1]=(__bf16)v.y; d.b[2]=(__bf16)v.z; d.b[3]=(__bf16)v.w;
      *reinterpret_cast<unsigned long long*>(Wt + ((long)sel*H_ + o)*(2*H_) + k4) = d.u;
    } else {
      int rem = gid - 2*H_*384;
      int row = rem / 192;
      int k4 = (rem % 192) * 4;
      V8 d;
      if (row < NC_) {
        float4 v = *reinterpret_cast<const float4*>(clsW + (long)row*H_ + k4);
        d.b[0]=(__bf16)v.x; d.b[1]=(__bf16)v.y; d.b[2]=(__bf16)v.z; d.b[3]=(__bf16)v.w;
      } else {
        d.b[0]=d.b[1]=d.b[2]=d.b[3]=(__bf16)0.f;
      }
      *reinterpret_cast<unsigned long long*>(clsA + (long)row*H_ + k4) = d.u;
    }
  } else if (blk < S1_CVT + S1_TPS) {
    int b = blk - S1_CVT;
    int bx = b % 24, by = (b / 24) % 32, bz = b / (24*32);
    const float* in = seq + (long)bz*L_*H_;
    __bf16* out = seqT + (long)bz*H_*L_;
    int c0 = bx*32, r0 = by*32;
    int tx = tid & 31, ty = tid >> 5;
#pragma unroll
    for (int p = 0; p < 4; ++p)
      t[ty + p*8][tx] = in[(long)(r0 + ty + p*8)*H_ + c0 + tx];
    __syncthreads();
#pragma unroll
    for (int p = 0; p < 4; ++p)
      out[(long)(c0 + ty + p*8)*L_ + r0 + tx] = (__bf16)t[tx][ty + p*8];
  } else if (blk < S1_CVT + S1_TPS + S1_POOL) {
    int be = blk - (S1_CVT + S1_TPS);
    int idx[M_]; float msk[M_];
#pragma unroll
    for (int m = 0; m < M_; ++m) {
      idx[m] = midx[be * M_ + m];
      msk[m] = mmask[be * M_ + m];
    }
    int b = be / NE_;
    const float* sb = seq + (size_t)b * L_ * H_;
    for (int h = tid; h < H_; h += 256) {
      float v[M_]; float mx = -3.0e38f;
#pragma unroll
      for (int m = 0; m < M_; ++m) {
        float x = (msk[m] > 0.f) ? sb[(size_t)idx[m] * H_ + h] : -1e30f;
        v[m] = x; mx = fmaxf(mx, x);
      }
      float s = 0.f;
#pragma unroll
      for (int m = 0; m < M_; ++m) s += expf(v[m] - mx);
      e_embB[(size_t)be * H_ + h] = (__bf16)(mx + logf(s));
    }
  } else {
    int i = (blk - (S1_CVT + S1_TPS + S1_POOL))*256 + tid;
    int l4 = (i & 255) * 4;
    int nh = (i >> 8) % NH_;
    int be = i / (256 * NH_);
    int b  = be / NE_;
    float s0=0.f, s1=0.f, s2=0.f, s3=0.f, cnt=0.f;
#pragma unroll
    for (int m = 0; m < M_; ++m) {
      float mk = mmask[be*M_ + m];
      cnt += mk;
      int id = midx[be*M_ + m];
      float4 a = *reinterpret_cast<const float4*>(
          att + (((size_t)b*NH_ + nh)*L_ + id)*L_ + l4);
      s0 += mk*a.x; s1 += mk*a.y; s2 += mk*a.z; s3 += mk*a.w;
    }
    float inv = 1.f / fmaxf(cnt, 1.f);
    V8 o;
    o.b[0]=(__bf16)(s0*inv); o.b[1]=(__bf16)(s1*inv);
    o.b[2]=(__bf16)(s2*inv); o.b[3]=(__bf16)(s3*inv);
    *reinterpret_cast<unsigned long long*>(e_att + ((size_t)be*NH_ + nh)*L_ + l4) = o.u;
  }
}

// =================== STAGE 2: fused wc(NN) + htatt + pre ===================
// [0,384) wc | [384,2784) htatt | [2784,2832) pre
#define S2_WC  384
#define S2_HT  2400
#define S2_PRE 48

__global__ __launch_bounds__(256) void k_mid(
    const __bf16* __restrict__ clsA, const float* __restrict__ projW,
    const __bf16* __restrict__ e_att, const int* __restrict__ hts,
    const __bf16* __restrict__ e_embB, const __bf16* __restrict__ Wt,
    __bf16* __restrict__ WcT, __bf16* __restrict__ htatt,
    float* __restrict__ hpre, float* __restrict__ tpre)
{
  __shared__ __bf16 sm[2*64*40];
  int blk = blockIdx.x;
  int tid = threadIdx.x;
  if (blk < S2_WC) {
    int n0 = (blk % 192)*64, r0 = (blk / 192)*64;
    floatx4 acc[2][2] = {};
    gemm_core_nn(clsA, H_, r0, projW, EMB_*BS_, n0, H_, sm, acc);
    int lid = tid & 63, w = tid >> 6;
    int ar = (w&1)*32, bc = (w>>1)*32, frow = lid&15, kg = lid>>4;
#pragma unroll
    for (int i = 0; i < 2; ++i)
#pragma unroll
      for (int r = 0; r < 4; ++r) {
        int c = r0 + ar + i*16 + kg*4 + r;
#pragma unroll
        for (int j = 0; j < 2; ++j)
          WcT[(long)c*(EMB_*BS_) + n0 + bc + j*16 + frow] = (__bf16)acc[i][j][r];
      }
  } else if (blk < S2_WC + S2_HT) {
    int bp = blk - S2_WC;
    int b = bp / P_;
    int hi = hts[bp*2 + 0], ti = hts[bp*2 + 1];
    const __bf16* ha = e_att + (size_t)(b*NE_ + hi) * NH_ * L_;
    const __bf16* ta = e_att + (size_t)(b*NE_ + ti) * NH_ * L_;
    int l4 = tid * 4;
    float v[4] = {0.f,0.f,0.f,0.f};
#pragma unroll
    for (int nh = 0; nh < NH_; ++nh) {
      V8 x, y;
      x.u = *reinterpret_cast<const unsigned long long*>(ha + nh*L_ + l4);
      y.u = *reinterpret_cast<const unsigned long long*>(ta + nh*L_ + l4);
#pragma unroll
      for (int q = 0; q < 4; ++q) v[q] += (float)x.b[q] * (float)y.b[q];
    }
    float loc = 0.f;
#pragma unroll
    for (int q = 0; q < 4; ++q) { v[q] *= (1.f/NH_); loc += v[q]; }
    float* red = reinterpret_cast<float*>(sm);
    for (int off = 32; off > 0; off >>= 1) loc += __shfl_down(loc, off, 64);
    if ((tid & 63) == 0) red[tid >> 6] = loc;
    __syncthreads();
    float inv = 1.f / (red[0] + red[1] + red[2] + red[3] + 1e-30f);
    V8 o;
#pragma unroll
    for (int q = 0; q < 4; ++q) o.b[q] = (__bf16)(v[q] * inv);
    *reinterpret_cast<unsigned long long*>(htatt + (size_t)bp*L_ + l4) = o.u;
  } else {
    int tb = blk - (S2_WC + S2_HT);
    int o0 = (tb % 12)*64;
    int r0 = ((tb / 12) & 1)*64;
    int sel = tb / 24;
    floatx4 acc[2][2] = {};
    gemm_core(e_embB, H_, r0, Wt + (long)sel*H_*(2*H_), 2*H_, o0, H_, sm, acc);
    float* out = sel ? tpre : hpre;
    int lid = tid & 63, w = tid >> 6;
    int ar = (w&1)*32, bc = (w>>1)*32, frow = lid&15, kg = lid>>4;
#pragma unroll
    for (int i = 0; i < 2; ++i)
#pragma unroll
      for (int r = 0; r < 4; ++r) {
        int be = r0 + ar + i*16 + kg*4 + r;
        if (be < B_*NE_) {
#pragma unroll
          for (int j = 0; j < 2; ++j)
            out[(long)be*EMB_ + o0 + bc + j*16 + frow] = acc[i][j][r];
        }
      }
  }
}

// =================== STAGE 3: rs ===================
__global__ __launch_bounds__(256) void k_rs_mfma(
    const __bf16* __restrict__ htatt, const __bf16* __restrict__ seqT,
    __bf16* __restrict__ rs)
{
  __shared__ __bf16 sm[2*64*40];
  int b = blockIdx.z, p0 = blockIdx.y*64, h0 = blockIdx.x*64;
  floatx4 acc[2][2] = {};
  gemm_core(htatt, L_, (long)b*P_ + p0, seqT + (long)b*H_*L_, L_, h0, L_, sm, acc);
  int lid = threadIdx.x & 63, w = threadIdx.x >> 6;
  int ar = (w&1)*32, bc = (w>>1)*32, frow = lid&15, kg = lid>>4;
#pragma unroll
  for (int i = 0; i < 2; ++i)
#pragma unroll
    for (int r = 0; r < 4; ++r) {
      int p = p0 + ar + i*16 + kg*4 + r;
      if (p < P_) {
#pragma unroll
        for (int j = 0; j < 2; ++j)
          rs[((long)b*P_ + p)*H_ + h0 + bc + j*16 + frow] = (__bf16)acc[i][j][r];
      }
    }
}

// =================== STAGE 4: extract (64x128 tiles) ===================
__global__ __launch_bounds__(256) void k_extract_mfma(
    const __bf16* __restrict__ rs, const __bf16* __restrict__ Wt,
    const float* __restrict__ headb, const float* __restrict__ tailb,
    const float* __restrict__ hpre, const float* __restrict__ tpre,
    const int* __restrict__ hts, __bf16* __restrict__ hs, __bf16* __restrict__ ts)
{
  __shared__ __bf16 sm[(64+128)*40];
  int sel = blockIdx.z, r0 = blockIdx.y*64, o0 = blockIdx.x*128;
  const float* bias = sel ? tailb : headb;
  const float* pre = sel ? tpre : hpre;
  __bf16* out = sel ? ts : hs;
  floatx4 acc[2][4] = {};
  gemm_core_wide(rs, H_, r0, Wt + (long)sel*H_*(2*H_) + H_, 2*H_, o0, H_, sm, acc);
  int lid = threadIdx.x & 63, w = threadIdx.x >> 6;
  int ar = (w&1)*32, bc = (w>>1)*64, frow = lid&15, kg = lid>>4;
#pragma unroll
  for (int i = 0; i < 2; ++i)
#pragma unroll
    for (int r = 0; r < 4; ++r) {
      int row = r0 + ar + i*16 + kg*4 + r;
      if (row < B_*P_) {
        int b = row / P_;
        int e = hts[row*2 + sel];
        const float* prow = pre + (long)(b*NE_ + e) * EMB_;
#pragma unroll
        for (int q = 0; q < 4; ++q) {
          int o = o0 + bc + q*16 + frow;
          out[(long)row*EMB_ + o] = (__bf16)tanhf(acc[i][q][r] + prow[o] + bias[o]);
        }
      }
    }
}

// =================== STAGE 5: logits split-K x2 ===================
__global__ __launch_bounds__(512) void k_logits_mfma(
    const __bf16* __restrict__ hs, const __bf16* __restrict__ ts,
    const __bf16* __restrict__ WcT, float* __restrict__ partial)
{
  int r0 = blockIdx.x * 16;
  int kh = blockIdx.y;                 // 0..1
  int tid = threadIdx.x;
  int w = tid >> 6, lid = tid & 63;
  int frow = lid & 15, kg = lid >> 4;
  int row = r0 + frow;
  long hsrow = (long)row * EMB_;
  floatx4 acc[7] = {};
  int kbase0 = kh*6144 + w*768;
  for (int s = 0; s < 24; ++s) {
    int kb = kbase0 + s*32 + kg*8;
    int q16 = (kb >> 8) << 4;
    int ii = (kb >> 4) & 15;
    int jj0 = kb & 15;
    float hv = (float)hs[hsrow + q16 + ii];
    V16 tsv; tsv.q = *reinterpret_cast<const uint4*>(ts + hsrow + q16 + jj0);
    bf16x8 af;
#pragma unroll
    for (int j = 0; j < 8; ++j) af[j] = (__bf16)(hv * (float)tsv.b[j]);
#pragma unroll
    for (int f = 0; f < 7; ++f) {
      V16 bv; bv.q = *reinterpret_cast<const uint4*>(WcT + (long)(f*16 + frow)*(EMB_*BS_) + kb);
      acc[f] = __builtin_amdgcn_mfma_f32_16x16x32_bf16(af, bv.v, acc[f], 0, 0, 0);
    }
  }
  __shared__ float red[8][16][112];
#pragma unroll
  for (int f = 0; f < 7; ++f)
#pragma unroll
    for (int r = 0; r < 4; ++r)
      red[w][kg*4 + r][f*16 + frow] = acc[f][r];
  __syncthreads();
  for (int e = tid; e < 16*112; e += 512) {
    int rr = e / 112, cc = e % 112;
    float s = 0.f;
#pragma unroll
    for (int ww = 0; ww < 8; ++ww) s += red[ww][rr][cc];
    partial[((long)kh*B_*P_ + r0 + rr)*112 + cc] = s;
  }
}

// =================== STAGE 6: reduce ===================
__global__ __launch_bounds__(256) void k_lred(
    const float* __restrict__ partial, const float* __restrict__ clsb,
    float* __restrict__ out)
{
  int gid = blockIdx.x*256 + threadIdx.x;
  if (gid >= B_*P_*112) return;
  int row = gid / 112, c = gid % 112;
  if (c < NC_)
    out[(long)row*NC_ + c] = partial[(long)row*112 + c]
                           + partial[((long)B_*P_ + row)*112 + c] + clsb[c];
}

extern "C" void kernel_launch(void* const* d_in, const int* in_sizes, int n_in,
                              void* d_out, int out_size, void* d_ws, size_t ws_size,
                              hipStream_t stream) {
  const float* seq   = (const float*)d_in[0];
  const float* att   = (const float*)d_in[1];
  const float* headW = (const float*)d_in[2];
  const float* headb = (const float*)d_in[3];
  const float* tailW = (const float*)d_in[4];
  const float* tailb = (const float*)d_in[5];
  const float* projW = (const float*)d_in[6];
  const float* clsW  = (const float*)d_in[7];
  const float* clsb  = (const float*)d_in[8];
  const float* mmask = (const float*)d_in[9];
  const int* midx = (const int*)d_in[10];
  const int* hts  = (const int*)d_in[11];

  char* p = (char*)d_ws;
  auto alloc_f = [&](size_t n){ float* r = (float*)p; p += n*sizeof(float); return r; };
  auto alloc_b = [&](size_t n){ __bf16* r = (__bf16*)p; p += n*2; return r; };
  float* hpre    = alloc_f((size_t)B_*NE_*EMB_);
  float* tpre    = alloc_f((size_t)B_*NE_*EMB_);
  float* partial = alloc_f((size_t)2*B_*P_*112);
  __bf16* e_embB = alloc_b((size_t)128*H_);
  __bf16* e_att  = alloc_b((size_t)B_*NE_*NH_*L_);
  __bf16* htattb = alloc_b((size_t)2464*L_);
  __bf16* seqT   = alloc_b((size_t)B_*H_*L_);
  __bf16* rsb    = alloc_b((size_t)2432*H_);
  __bf16* Wt     = alloc_b((size_t)2*H_*2*H_);
  __bf16* clsA   = alloc_b((size_t)128*H_);
  __bf16* WcT    = alloc_b((size_t)128*EMB_*BS_);
  __bf16* hsb    = alloc_b((size_t)2432*EMB_);
  __bf16* tsb    = alloc_b((size_t)2432*EMB_);

  k_prep<<<S1_CVT + S1_TPS + S1_POOL + S1_ATT, 256, 0, stream>>>(
      seq, att, headW, tailW, clsW, mmask, midx,
      Wt, clsA, seqT, e_embB, e_att);
  k_mid<<<S2_WC + S2_HT + S2_PRE, 256, 0, stream>>>(
      clsA, projW, e_att, hts, e_embB, Wt, WcT, htattb, hpre, tpre);
  k_rs_mfma<<<dim3(H_/64, 10, B_), 256, 0, stream>>>(htattb, seqT, rsb);
  k_extract_mfma<<<dim3(EMB_/128, 38, 2), 256, 0, stream>>>(
      rsb, Wt, headb, tailb, hpre, tpre, hts, hsb, tsb);
  k_logits_mfma<<<dim3(150, 2), 512, 0, stream>>>(hsb, tsb, WcT, partial);
  k_lred<<<(B_*P_*112 + 255)/256, 256, 0, stream>>>(partial, clsb, (float*)d_out);
}